// Round 1
// baseline (1215.226 us; speedup 1.0000x reference)
//
#include <hip/hip_runtime.h>
#include <stdint.h>

#define K 27
#define S 258

// ---------- fill out_key region with -1.0f ----------
__global__ void fill_f32(float* __restrict__ p, int n, float v) {
    int i = blockIdx.x * blockDim.x + threadIdx.x;
    if (i < n) p[i] = v;
}

__device__ __forceinline__ int compute_enc(const int* __restrict__ si, int N,
                                           int e, int* out_n, int* out_m) {
    int n = e / K; int m = e - n * K;
    *out_n = n; *out_m = m;
    int b = si[n], x = si[N + n], y = si[2 * N + n], z = si[3 * N + n];
    int ox = m / 9; int rm = m - ox * 9; int oy = rm / 3; int oz = rm - oy * 3;
    // nbr = coord + (off-1) + HALF(=1) = coord + off, off in [0,2]
    return ((b * S + x + ox) * S + (y + oy)) * S + (z + oz);
}

// ---------- pass 1: insert keys, record min entry index per key ----------
__global__ void k_insert(const int* __restrict__ si, int N, int NK,
                         int* __restrict__ keys, int* __restrict__ pos,
                         unsigned Cmask, int Cshift) {
    int e = blockIdx.x * blockDim.x + threadIdx.x;
    if (e >= NK) return;
    int n, m;
    int enc = compute_enc(si, N, e, &n, &m);
    unsigned h = ((unsigned)enc * 2654435761u) >> Cshift;
    while (true) {
        int old = atomicCAS(&keys[h], -1, enc);
        if (old == -1 || old == enc) { atomicMin(&pos[h], e); break; }
        h = (h + 1) & Cmask;
    }
}

// ---------- pass 2: flag first occurrences, remember slot ----------
__global__ void k_flag(const int* __restrict__ si, int N, int NK,
                       const int* __restrict__ keys, const int* __restrict__ pos,
                       int* __restrict__ slot_of, int* __restrict__ flags,
                       unsigned Cmask, int Cshift) {
    int e = blockIdx.x * blockDim.x + threadIdx.x;
    if (e >= NK) return;
    int n, m;
    int enc = compute_enc(si, N, e, &n, &m);
    unsigned h = ((unsigned)enc * 2654435761u) >> Cshift;
    while (keys[h] != enc) h = (h + 1) & Cmask;
    slot_of[e] = (int)h;
    flags[e] = (pos[h] == e) ? 1 : 0;
}

// ---------- scan A: per-4096-tile sums ----------
__global__ void k_scanA(const int* __restrict__ flags, int* __restrict__ bsums) {
    __shared__ int s[256];
    int tid = threadIdx.x;
    const int4* f4 = (const int4*)(flags + (size_t)blockIdx.x * 4096);
    int sum = 0;
    for (int j = tid; j < 1024; j += 256) {
        int4 v = f4[j];
        sum += v.x + v.y + v.z + v.w;
    }
    s[tid] = sum; __syncthreads();
    for (int off = 128; off > 0; off >>= 1) {
        if (tid < off) s[tid] += s[tid + off];
        __syncthreads();
    }
    if (tid == 0) bsums[blockIdx.x] = s[0];
}

// ---------- scan B: exclusive scan of tile sums (single block, NB<=1024) ----------
__global__ void k_scanB(int* __restrict__ bsums, int NB) {
    __shared__ int s[1024];
    int tid = threadIdx.x;
    int v = (tid < NB) ? bsums[tid] : 0;
    s[tid] = v; __syncthreads();
    for (int off = 1; off < 1024; off <<= 1) {
        int t = (tid >= off) ? s[tid - off] : 0;
        __syncthreads();
        s[tid] += t;
        __syncthreads();
    }
    if (tid < NB) bsums[tid] = s[tid] - v;  // exclusive
}

// ---------- scan C: final exclusive ranks; write out_key at first occurrences ----------
__global__ void k_scanC(int* __restrict__ r, const int* __restrict__ bsums,
                        const int* __restrict__ si, int N, int NK,
                        float* __restrict__ out_key) {
    __shared__ int s[256];
    int tid = threadIdx.x;
    int base = blockIdx.x * 4096 + tid * 16;
    int4 v0 = *(const int4*)(r + base);
    int4 v1 = *(const int4*)(r + base + 4);
    int4 v2 = *(const int4*)(r + base + 8);
    int4 v3 = *(const int4*)(r + base + 12);
    int vals[16] = {v0.x, v0.y, v0.z, v0.w, v1.x, v1.y, v1.z, v1.w,
                    v2.x, v2.y, v2.z, v2.w, v3.x, v3.y, v3.z, v3.w};
    int tsum = 0;
#pragma unroll
    for (int j = 0; j < 16; j++) tsum += vals[j];
    s[tid] = tsum; __syncthreads();
    for (int off = 1; off < 256; off <<= 1) {
        int t = (tid >= off) ? s[tid - off] : 0;
        __syncthreads();
        s[tid] += t;
        __syncthreads();
    }
    int excl = s[tid] - tsum;
    int offset = bsums[blockIdx.x] + excl;
    int run = 0;
#pragma unroll
    for (int j = 0; j < 16; j++) {
        int e = base + j;
        int rank = offset + run;
        int flag = vals[j];
        if (flag && e < NK) {
            int n = e / K; int m = e - n * K;
            int x = si[N + n], y = si[2 * N + n], z = si[3 * N + n];
            int ox = m / 9; int rm = m - ox * 9; int oy = rm / 3; int oz = rm - oy * 3;
            out_key[(size_t)rank * 3 + 0] = (float)(x + ox - 1);
            out_key[(size_t)rank * 3 + 1] = (float)(y + oy - 1);
            out_key[(size_t)rank * 3 + 2] = (float)(z + oz - 1);
        }
        r[e] = rank;
        run += flag;
    }
}

// ---------- pass 4a: kernel_map + uid per entry ----------
__global__ void k_map(int* __restrict__ slot_of, const int* __restrict__ pos,
                      const int* __restrict__ r, float* __restrict__ km, int NK) {
    int e = blockIdx.x * blockDim.x + threadIdx.x;
    if (e >= NK) return;
    int h = slot_of[e];
    int p = pos[h];
    int uid = r[p];
    int n = e / K; int m = e - n * K;
    km[(size_t)e * 3 + 0] = (float)n;
    km[(size_t)e * 3 + 1] = (float)uid;
    km[(size_t)e * 3 + 2] = (float)m;
    slot_of[e] = uid;  // reuse as uid array for scatter
}

// ---------- pass 4b: segment-sum scatter (1 thread per (entry, feature)) ----------
__global__ void k_scatter(const int* __restrict__ uid_arr,
                          const float* __restrict__ feat,
                          float* __restrict__ outF, int NK) {
    int idx = blockIdx.x * blockDim.x + threadIdx.x;
    if (idx >= NK * 32) return;
    int e = idx >> 5; int f = idx & 31;
    int uid = uid_arr[e];
    int n = e / K;
    atomicAdd(&outF[(size_t)uid * 32 + f], feat[(size_t)n * 32 + f]);
}

extern "C" void kernel_launch(void* const* d_in, const int* in_sizes, int n_in,
                              void* d_out, int out_size, void* d_ws, size_t ws_size,
                              hipStream_t stream) {
    const int* si = (const int*)d_in[0];
    const float* feat = (const float*)d_in[1];
    int N = in_sizes[0] / 4;
    int NK = N * K;                           // 2,700,000
    int NKp = (NK + 4095) & ~4095;            // padded to 4096 tiles
    int NB = NKp / 4096;                      // ~660 (<=1024 required)

    float* km = (float*)d_out;                // [NK,3]
    float* out_key = km + (size_t)NK * 3;     // [NK,3]
    float* outF = km + (size_t)NK * 6;        // [NK,32]

    // workspace layout
    int Cbits = 23;
    size_t need = ((size_t)8 << Cbits) + (size_t)NKp * 8 + (size_t)NB * 4 + 1024;
    if (need > ws_size) Cbits = 22;           // smaller table fallback
    unsigned C = 1u << Cbits;
    unsigned Cmask = C - 1;
    int Cshift = 32 - Cbits;
    char* w = (char*)d_ws;
    int* keys    = (int*)w; w += (size_t)C * 4;
    int* pos     = (int*)w; w += (size_t)C * 4;
    int* slot_of = (int*)w; w += (size_t)NKp * 4;
    int* r       = (int*)w; w += (size_t)NKp * 4;
    int* bsums   = (int*)w;

    // init
    hipMemsetAsync(keys, 0xFF, (size_t)C * 4, stream);          // keys = -1
    hipMemsetAsync(pos, 0x7F, (size_t)C * 4, stream);           // pos = big
    if (NKp > NK) hipMemsetAsync(r + NK, 0, (size_t)(NKp - NK) * 4, stream);
    hipMemsetAsync(outF, 0, (size_t)NK * 32 * 4, stream);       // out_feats = 0
    fill_f32<<<(NK * 3 + 255) / 256, 256, 0, stream>>>(out_key, NK * 3, -1.0f);

    int nb1 = (NK + 255) / 256;
    k_insert<<<nb1, 256, 0, stream>>>(si, N, NK, keys, pos, Cmask, Cshift);
    k_flag<<<nb1, 256, 0, stream>>>(si, N, NK, keys, pos, slot_of, r, Cmask, Cshift);
    k_scanA<<<NB, 256, 0, stream>>>(r, bsums);
    k_scanB<<<1, 1024, 0, stream>>>(bsums, NB);
    k_scanC<<<NB, 256, 0, stream>>>(r, bsums, si, N, NK, out_key);
    k_map<<<nb1, 256, 0, stream>>>(slot_of, pos, r, km, NK);
    long total = (long)NK * 32;
    k_scatter<<<(int)((total + 255) / 256), 256, 0, stream>>>(slot_of, feat, outF, NK);
}

// Round 2
// 844.956 us; speedup vs baseline: 1.4382x; 1.4382x over previous
//
#include <hip/hip_runtime.h>
#include <stdint.h>

typedef unsigned long long u64;

#define K 27
#define S 258
#define ENC_MASK 0x7FFFFFFu           // 27 bits
#define POS_MASK 0x3FFFFFu            // 22 bits
#define EMPTY 0xFFFFFFFFFFFFFFFFull
#define BIT63 (1ull << 63)

__device__ __forceinline__ unsigned enc_of(const int* __restrict__ si, int N,
                                           int e, int* out_n, int* out_m) {
    int n = e / K; int m = e - n * K;
    *out_n = n; *out_m = m;
    int b = si[n], x = si[N + n], y = si[2 * N + n], z = si[3 * N + n];
    int ox = m / 9; int rm = m - ox * 9; int oy = rm / 3; int oz = rm - oy * 3;
    // nbr+HALF = coord + off, off in [0,2]
    return (unsigned)(((b * S + x + ox) * S + (y + oy)) * S + (z + oz));
}

// ---------- pass 1: insert packed (pos<<27|enc); min-pos per key ----------
__global__ void k_insert(const int* __restrict__ si, int N, int NK,
                         u64* __restrict__ tab, unsigned Cmask, int Cshift) {
    int e = blockIdx.x * blockDim.x + threadIdx.x;
    if (e >= NK) return;
    int n, m;
    unsigned enc = enc_of(si, N, e, &n, &m);
    u64 desired = ((u64)e << 27) | enc;
    unsigned h = (enc * 2654435761u) >> Cshift;
    while (true) {
        u64 cur = tab[h];                         // plain read (stale-EMPTY ok)
        if (cur == EMPTY) {
            u64 old = atomicCAS(&tab[h], EMPTY, desired);
            if (old == EMPTY) return;             // claimed
            cur = old;                            // lost race; inspect actual
        }
        if ((unsigned)(cur & ENC_MASK) == enc) {  // same key: min over pos
            atomicMin(&tab[h], desired);
            return;
        }
        h = (h + 1) & Cmask;                      // other key: probe on
    }
}

// ---------- pass 2: flag first occurrences; mark multi rows via bit63 ----------
__global__ void k_flag(const int* __restrict__ si, int N, int NK,
                       u64* __restrict__ tab, int* __restrict__ slot_of,
                       int* __restrict__ flags, unsigned Cmask, int Cshift) {
    int e = blockIdx.x * blockDim.x + threadIdx.x;
    if (e >= NK) return;
    int n, m;
    unsigned enc = enc_of(si, N, e, &n, &m);
    unsigned h = (enc * 2654435761u) >> Cshift;
    u64 w;
    while ((unsigned)((w = tab[h]) & ENC_MASK) != enc) h = (h + 1) & Cmask;
    unsigned pos = (unsigned)((w >> 27) & POS_MASK);
    int f = (pos == (unsigned)e) ? 1 : 0;
    if (!f) atomicOr(&tab[h], BIT63);             // ~2% of entries only
    slot_of[e] = (int)h;
    flags[e] = f;
}

// ---------- scan A: per-4096-tile sums ----------
__global__ void k_scanA(const int* __restrict__ flags, int* __restrict__ bsums) {
    __shared__ int s[256];
    int tid = threadIdx.x;
    const int4* f4 = (const int4*)(flags + (size_t)blockIdx.x * 4096);
    int sum = 0;
    for (int j = tid; j < 1024; j += 256) {
        int4 v = f4[j];
        sum += v.x + v.y + v.z + v.w;
    }
    s[tid] = sum; __syncthreads();
    for (int off = 128; off > 0; off >>= 1) {
        if (tid < off) s[tid] += s[tid + off];
        __syncthreads();
    }
    if (tid == 0) bsums[blockIdx.x] = s[0];
}

// ---------- scan B: exclusive scan of tile sums; total -> bsums[NB] ----------
__global__ void k_scanB(int* __restrict__ bsums, int NB) {
    __shared__ int s[1024];
    int tid = threadIdx.x;
    int v = (tid < NB) ? bsums[tid] : 0;
    s[tid] = v; __syncthreads();
    for (int off = 1; off < 1024; off <<= 1) {
        int t = (tid >= off) ? s[tid - off] : 0;
        __syncthreads();
        s[tid] += t;
        __syncthreads();
    }
    if (tid == 1023) bsums[NB] = s[1023];         // total unique count U
    if (tid < NB) bsums[tid] = s[tid] - v;        // exclusive
}

// ---------- scan C: ranks; write out_key + store uid into hash slot ----------
__global__ void k_scanC(const int* __restrict__ r, const int* __restrict__ bsums,
                        const int* __restrict__ si, const int* __restrict__ slot_of,
                        u64* __restrict__ tab, int N, int NK,
                        float* __restrict__ out_key) {
    __shared__ int s[256];
    int tid = threadIdx.x;
    int base = blockIdx.x * 4096 + tid * 16;
    int4 v0 = *(const int4*)(r + base);
    int4 v1 = *(const int4*)(r + base + 4);
    int4 v2 = *(const int4*)(r + base + 8);
    int4 v3 = *(const int4*)(r + base + 12);
    int vals[16] = {v0.x, v0.y, v0.z, v0.w, v1.x, v1.y, v1.z, v1.w,
                    v2.x, v2.y, v2.z, v2.w, v3.x, v3.y, v3.z, v3.w};
    int tsum = 0;
#pragma unroll
    for (int j = 0; j < 16; j++) tsum += vals[j];
    s[tid] = tsum; __syncthreads();
    for (int off = 1; off < 256; off <<= 1) {
        int t = (tid >= off) ? s[tid - off] : 0;
        __syncthreads();
        s[tid] += t;
        __syncthreads();
    }
    int excl = s[tid] - tsum;
    int offset = bsums[blockIdx.x] + excl;
    int run = 0;
#pragma unroll
    for (int j = 0; j < 16; j++) {
        int e = base + j;
        int rank = offset + run;
        int flag = vals[j];
        if (flag && e < NK) {
            int n = e / K; int m = e - n * K;
            int x = si[N + n], y = si[2 * N + n], z = si[3 * N + n];
            int ox = m / 9; int rm = m - ox * 9; int oy = rm / 3; int oz = rm - oy * 3;
            out_key[(size_t)rank * 3 + 0] = (float)(x + ox - 1);
            out_key[(size_t)rank * 3 + 1] = (float)(y + oy - 1);
            out_key[(size_t)rank * 3 + 2] = (float)(z + oz - 1);
            int h = slot_of[e];
            u64 old = tab[h];                     // sole writer for this slot
            tab[h] = (old & BIT63) | (u64)(unsigned)rank;
        }
        run += flag;
    }
}

// ---------- kernel_map + (uid,multi) per entry ----------
__global__ void k_map(int* __restrict__ slot_of, const u64* __restrict__ tab,
                      float* __restrict__ km, int NK) {
    int e = blockIdx.x * blockDim.x + threadIdx.x;
    if (e >= NK) return;
    int h = slot_of[e];
    u64 w = tab[h];
    unsigned uid = (unsigned)(w & POS_MASK);
    unsigned multi = (unsigned)(w >> 63);
    int n = e / K; int m = e - n * K;
    km[(size_t)e * 3 + 0] = (float)n;
    km[(size_t)e * 3 + 1] = (float)uid;
    km[(size_t)e * 3 + 2] = (float)m;
    slot_of[e] = (int)((uid << 1) | multi);       // reuse for scatter
}

// ---------- zero outF rows that have >1 contributor ----------
__global__ void k_zmulti(const u64* __restrict__ tab, float4* __restrict__ outF4,
                         unsigned C) {
    unsigned h = blockIdx.x * blockDim.x + threadIdx.x;
    if (h >= C) return;
    u64 w = tab[h];
    if (w != EMPTY && (w >> 63)) {
        unsigned uid = (unsigned)(w & POS_MASK);
        float4 z = {0.f, 0.f, 0.f, 0.f};
        float4* p = outF4 + (size_t)uid * 8;
#pragma unroll
        for (int j = 0; j < 8; j++) p[j] = z;
    }
}

// ---------- tail: rows >= U -> outF=0, out_key=-1 ----------
__global__ void k_tail(const int* __restrict__ bsums, int NB, int NK,
                       float* __restrict__ out_key, float4* __restrict__ outF4) {
    int U = bsums[NB];
    int rows = NK - U;
    for (int i = blockIdx.x * blockDim.x + threadIdx.x; i < rows;
         i += gridDim.x * blockDim.x) {
        int row = U + i;
        float4 z = {0.f, 0.f, 0.f, 0.f};
        float4* p = outF4 + (size_t)row * 8;
#pragma unroll
        for (int j = 0; j < 8; j++) p[j] = z;
        out_key[(size_t)row * 3 + 0] = -1.0f;
        out_key[(size_t)row * 3 + 1] = -1.0f;
        out_key[(size_t)row * 3 + 2] = -1.0f;
    }
}

// ---------- scatter: float4 per (entry, group); atomics only for multi rows ----
__global__ void k_scatter(const int* __restrict__ uidm,
                          const float4* __restrict__ feat4,
                          float* __restrict__ outF, int NK) {
    int idx = blockIdx.x * blockDim.x + threadIdx.x;   // NK*8 threads
    if (idx >= NK * 8) return;
    int e = idx >> 3; int g = idx & 7;
    int pm = uidm[e];
    unsigned uid = ((unsigned)pm) >> 1;
    int n = e / K;
    float4 v = feat4[(size_t)n * 8 + g];
    float* p = outF + (size_t)uid * 32 + g * 4;
    if (pm & 1) {
        atomicAdd(p + 0, v.x);
        atomicAdd(p + 1, v.y);
        atomicAdd(p + 2, v.z);
        atomicAdd(p + 3, v.w);
    } else {
        *(float4*)p = v;
    }
}

extern "C" void kernel_launch(void* const* d_in, const int* in_sizes, int n_in,
                              void* d_out, int out_size, void* d_ws, size_t ws_size,
                              hipStream_t stream) {
    const int* si = (const int*)d_in[0];
    const float* feat = (const float*)d_in[1];
    int N = in_sizes[0] / 4;
    int NK = N * K;                            // 2,700,000
    int NKp = (NK + 4095) & ~4095;
    int NB = NKp / 4096;                       // ~660

    float* km = (float*)d_out;                 // [NK,3]
    float* out_key = km + (size_t)NK * 3;      // [NK,3]
    float* outF = km + (size_t)NK * 6;         // [NK,32]

    int Cbits = 23;
    size_t need = ((size_t)8 << Cbits) + (size_t)NKp * 8 + (size_t)(NB + 1) * 4 + 64;
    if (need > ws_size) Cbits = 22;
    unsigned C = 1u << Cbits;
    unsigned Cmask = C - 1;
    int Cshift = 32 - Cbits;

    char* w = (char*)d_ws;
    u64* tab     = (u64*)w; w += (size_t)C * 8;
    int* slot_of = (int*)w; w += (size_t)NKp * 4;
    int* flags   = (int*)w; w += (size_t)NKp * 4;
    int* bsums   = (int*)w;

    // init (only the table + scan padding — no 346MB outF memset anymore)
    hipMemsetAsync(tab, 0xFF, (size_t)C * 8, stream);             // EMPTY
    if (NKp > NK) hipMemsetAsync(flags + NK, 0, (size_t)(NKp - NK) * 4, stream);

    int nb1 = (NK + 255) / 256;
    k_insert<<<nb1, 256, 0, stream>>>(si, N, NK, tab, Cmask, Cshift);
    k_flag<<<nb1, 256, 0, stream>>>(si, N, NK, tab, slot_of, flags, Cmask, Cshift);
    k_scanA<<<NB, 256, 0, stream>>>(flags, bsums);
    k_scanB<<<1, 1024, 0, stream>>>(bsums, NB);
    k_scanC<<<NB, 256, 0, stream>>>(flags, bsums, si, slot_of, tab, N, NK, out_key);
    k_map<<<nb1, 256, 0, stream>>>(slot_of, tab, km, NK);
    k_zmulti<<<(C + 255) / 256, 256, 0, stream>>>(tab, (float4*)outF, C);
    k_tail<<<512, 256, 0, stream>>>(bsums, NB, NK, out_key, (float4*)outF);
    k_scatter<<<(NK * 8 + 255) / 256, 256, 0, stream>>>(slot_of, (const float4*)feat,
                                                        outF, NK);
}